// Round 5
// baseline (182.969 us; speedup 1.0000x reference)
//
#include <hip/hip_runtime.h>
#include <hip/hip_bf16.h>
#include <math.h>

#define NS 4096      // samples
#define NC 512       // clusters
#define ND 64        // feature dim
#define NK 10        // classes
#define NPAIR 2080   // upper-triangle pairs (e<=d) of 64x64
#define KP 2176      // 2080 + 64 (linear) + 1 (const) + 31 zero-pad; 68*32
#define BOFF 2080
#define KOFF 2144
#define KSPLIT 4
#define KT_PER (KP / 32 / KSPLIT)   // 17 k-chunks per split block
#define ZB 1024                     // d2-zeroing blocks
#define QB 2048                     // Q-precompute blocks (2 rows each)

// workspace-layout deltas in shorts (launcher offsets are fixed)
#define QLOFF 8912896ull            // (Ql - Qh)
#define BLOFF 1114112ull            // (Bpl - Bph)

typedef __attribute__((ext_vector_type(8))) short short8;
typedef __attribute__((ext_vector_type(4))) float floatx4;

__device__ inline unsigned short f2b(float x) {
    __hip_bfloat16 h = __float2bfloat16(x);           // RNE
    return __builtin_bit_cast(unsigned short, h);
}
__device__ inline float b2f(unsigned short u) {
    __hip_bfloat16 h = __builtin_bit_cast(__hip_bfloat16, u);
    return __bfloat162float(h);
}

// true v_readlane_b32 (lane is a compile-time literal at every use site)
__device__ inline float rlane(float v, int k) {
    return __builtin_bit_cast(float, __builtin_amdgcn_readlane(__builtin_bit_cast(int, v), k));
}

// ---------------- (e,d) table with sentinels: val[p] = z[e]*z[d] ------------
__global__ void table_kernel(uchar2* __restrict__ edt) {
    const int e = threadIdx.x;                        // 64 threads
    int off = e * 64 - (e * (e - 1)) / 2;             // row e starts here
    for (int d = e; d < 64; ++d) edt[off + d - e] = make_uchar2(e, d);
    edt[BOFF + e] = make_uchar2(e, 64);               // linear terms: z*1
    if (e == 0) edt[KOFF] = make_uchar2(64, 64);      // const term: 1
    if (e < KP - KOFF - 1) edt[KOFF + 1 + e] = make_uchar2(65, 65);   // pad: 0
}

// ---------------- prep: 3 roles ---------------------------------------------
//  role A (blk <  NC):            Sigma^-1 (4-wave coop GJ) + beta pack
//  role B (NC <= blk < NC+ZB):    d2 zeroing
//  role C (blk >= NC+ZB):         Q precompute: Qh/Ql[4096][2176] bf16 hi/lo
//     pair products (bit-identical expression to the old in-gemm A-build).
__global__ __launch_bounds__(256, 4) void prep_kernel(
    const float* __restrict__ data, const float* __restrict__ S,
    const float* __restrict__ n, const float* __restrict__ mu,
    const int* __restrict__ clab, const uchar2* __restrict__ edt,
    unsigned short* __restrict__ Qh, unsigned short* __restrict__ Ql,
    unsigned short* __restrict__ Bph, unsigned short* __restrict__ Bpl,
    float* __restrict__ d2, float* __restrict__ labf)
{
    __shared__ float AcolS[ND * (ND + 1)];            // Sinv mirror [64][65]
    __shared__ float cbuf[ND];                        // bvec staging
    __shared__ float rowbuf[2][ND];                   // GJ pivot-row broadcast
    __shared__ float kksS[1];
    __shared__ float zq[2][66];                       // Q-role rows + sentinels

    if (blockIdx.x >= NC + ZB) {                      // ---- role C: Q build --
        const int qb = blockIdx.x - (NC + ZB);        // 0..QB-1
        const int half = threadIdx.x >> 7;            // 2 rows per block
        const int i = threadIdx.x & 127;              // 2 waves per row
        const int row = qb * 2 + half;
        if (i < 64) zq[half][i] = data[(size_t)row * ND + i];
        else if (i == 64) { zq[half][64] = 1.0f; zq[half][65] = 0.0f; }
        __syncthreads();
        const float* __restrict__ zr = zq[half];
        unsigned short* __restrict__ qh = Qh + (size_t)row * KP;
        unsigned short* __restrict__ ql = Ql + (size_t)row * KP;
        #pragma unroll
        for (int t = 0; t < 17; ++t) {                // 17*128 = 2176
            const int p = t * 128 + i;
            const uchar2 ed = edt[p];
            const float v = zr[ed.x] * zr[ed.y];
            const unsigned short h = f2b(v);
            const unsigned short l = f2b(v - b2f(h));
            qh[p] = h;
            ql[p] = l;
        }
        return;
    }

    if (blockIdx.x >= NC) {                           // ---- role B: d2 zero --
        const size_t base = (size_t)(blockIdx.x - NC) * 2048 + threadIdx.x * 8;
        *(float4*)&d2[base]     = make_float4(0.f, 0.f, 0.f, 0.f);
        *(float4*)&d2[base + 4] = make_float4(0.f, 0.f, 0.f, 0.f);
        return;
    }

    // ---- role A: 4-wave cooperative Gauss-Jordan (R16) ----
    const int c = blockIdx.x;
    const int tid = threadIdx.x;
    const int j = tid & 63;                           // column owned by lane
    const int w = tid >> 6;                           // wave -> rows 16w..16w+15
    const int rbase = w * 16;

    const float inv_nc = 1.0f / n[c];
    const float* __restrict__ Sc = S + (size_t)c * ND * ND + j;

    float4 B0, B1, B2, B3;
#define LOADR(u) {                                                   \
    const float x0 = Sc[(rbase + 4*(u) + 0) * ND] * inv_nc;          \
    const float x1 = Sc[(rbase + 4*(u) + 1) * ND] * inv_nc;          \
    const float x2 = Sc[(rbase + 4*(u) + 2) * ND] * inv_nc;          \
    const float x3 = Sc[(rbase + 4*(u) + 3) * ND] * inv_nc;          \
    B##u.x = (rbase + 4*(u) + 0 == j) ? x0 + 1e-6f : x0;             \
    B##u.y = (rbase + 4*(u) + 1 == j) ? x1 + 1e-6f : x1;             \
    B##u.z = (rbase + 4*(u) + 2 == j) ? x2 + 1e-6f : x2;             \
    B##u.w = (rbase + 4*(u) + 3 == j) ? x3 + 1e-6f : x3; }
    LOADR(0) LOADR(1) LOADR(2) LOADR(3)
#undef LOADR

#define UPD4(u, K) {                                                  \
    const float c0 = rlane(B##u.x, K);                                \
    const float c1 = rlane(B##u.y, K);                                \
    const float c2 = rlane(B##u.z, K);                                \
    const float c3 = rlane(B##u.w, K);                                \
    B##u.x = (om && (4*(u)+0 == ((K)&15))) ? rowk : B##u.x * am - c0 * rowk; \
    B##u.y = (om && (4*(u)+1 == ((K)&15))) ? rowk : B##u.y * am - c1 * rowk; \
    B##u.z = (om && (4*(u)+2 == ((K)&15))) ? rowk : B##u.z * am - c2 * rowk; \
    B##u.w = (om && (4*(u)+3 == ((K)&15))) ? rowk : B##u.w * am - c3 * rowk; \
}
#define STEPC(TL, C, K) {                                             \
    if (w == ((K) >> 4)) {                                            \
        const float rp = B##TL.C;         /* M[k][j]: own register */ \
        const float pv = rlane(rp, K);    /* pivot M[k][k] */         \
        const float ip = 1.0f / pv;                                   \
        rowbuf[(K) & 1][j] = (j == (K)) ? ip : rp * ip;               \
    }                                                                 \
    __syncthreads();                                                  \
    const float rowk = rowbuf[(K) & 1][j];                            \
    const float am = (j == (K)) ? 0.0f : 1.0f;                        \
    const bool om = (w == ((K) >> 4));                                \
    UPD4(0, K) UPD4(1, K) UPD4(2, K) UPD4(3, K)                       \
}
#define STEP4(T, TL) STEPC(TL, x, 4*(T)+0) STEPC(TL, y, 4*(T)+1) \
                     STEPC(TL, z, 4*(T)+2) STEPC(TL, w, 4*(T)+3)
#define FOR16P(M) M(0,0) M(1,1) M(2,2) M(3,3) M(4,0) M(5,1) M(6,2) M(7,3) \
                  M(8,0) M(9,1) M(10,2) M(11,3) M(12,0) M(13,1) M(14,2) M(15,3)
    FOR16P(STEP4)
#undef FOR16P
#undef STEP4
#undef STEPC
#undef UPD4

    // mirror Sinv into LDS for the pack gather (all 4 waves, disjoint rows)
#define MIR(u) *(float4*)&AcolS[j * (ND + 1) + rbase + 4*(u)] = B##u;
    MIR(0) MIR(1) MIR(2) MIR(3)
#undef MIR
    __syncthreads();                                  // AcolS complete

    if (w == 0) {                                     // y = Sinv*mu, kk, labels
        const float* __restrict__ muc = mu + (size_t)c * ND;
        float y = 0.f;
        #pragma unroll
        for (int t = 0; t < 16; ++t) {
            const float4 v = *(const float4*)&AcolS[j * (ND + 1) + 4 * t];
            y += v.x * muc[4*t]     + v.y * muc[4*t + 1]
               + v.z * muc[4*t + 2] + v.w * muc[4*t + 3];
        }
        cbuf[j] = -2.0f * y;                          // bvec values
        float kk = muc[j] * y;
        #pragma unroll
        for (int off = 32; off > 0; off >>= 1) kk += __shfl_down(kk, off);
        if (j == 0) {
            kksS[0] = kk;
            int lab = 0;
            for (int q = 0; q < NK; ++q) if (clab[c * NK + q] != 0) lab = q;
            labf[c] = (float)lab;
        }
    }
    __syncthreads();
    const float kks = kksS[0];

    unsigned short* __restrict__ ph = Bph + (size_t)c * KP;
    unsigned short* __restrict__ pl = Bpl + (size_t)c * KP;
    #pragma unroll
    for (int i = 0; i < 9; ++i) {                     // 34 iters split 4 ways
        const int t = w + 4 * i;
        if (t < KP / 64) {
            const int p = t * 64 + j;
            float val;
            if (p < NPAIR) {
                const uchar2 ed = edt[p];
                val = (ed.x == ed.y) ? AcolS[ed.x * (ND + 1) + ed.x]
                    : (AcolS[ed.y * (ND + 1) + ed.x] + AcolS[ed.x * (ND + 1) + ed.y]);
            } else if (p < KOFF) val = cbuf[p - BOFF];
            else if (p == KOFF)  val = kks;
            else                 val = 0.f;
            const unsigned short h = f2b(val);
            const unsigned short l = f2b(val - b2f(h));
            ph[p] = h;
            pl[p] = l;
        }
    }
}

// ---------------- d2 = Q·Beta^T, LDS-FREE register-double-buffered GEMM -----
// R20: R2-R4 all null (54us) because the barrier-coupled LDS phase structure,
// not bandwidth, was the wall (phase wall 7630cy vs max pipe ~2200cy). Key:
// B-frags have ZERO intra-block reuse (wave w reads rows w*64..+63, disjoint)
// -> LDS staging of B bought nothing and forced the mid-phase barrier. A-frags
// (4x reuse, 8KB/phase) are L1-served. So: per-lane direct global_load_dwordx4
// of all fragments, register ping/pong (static indexing, rule #20), ZERO
// barriers/LDS in the K-loop; waves free-run (m114 overlap regime); compiler
// emits exact counted vmcnt from register deps. Wave-scope coalescing: lanes
// (rlo,quad) cover 16 full 64B lines per instruction (quad = the 4x16B
// segments of one line). Same bits, same MFMA order -> d2 bit-identical.
__global__ __launch_bounds__(256, 2) void gemm_kernel(
    const unsigned short* __restrict__ Qh, const unsigned short* __restrict__ Ql,
    const unsigned short* __restrict__ Bph, const unsigned short* __restrict__ Bpl,
    float* __restrict__ d2)
{
    const int tid  = threadIdx.x;
    const int lane = tid & 63, w = tid >> 6;
    const int quad = lane >> 4, rlo = lane & 15;

    // T1 XCD remap: lid%8 selects (y,z) -> one B-slice per XCD (L2-resident)
    const int lid = blockIdx.x + 64 * blockIdx.y + 128 * blockIdx.z;
    const int nyz = lid & 7;
    const int m0 = (lid >> 3) * 64;               // sample tile
    const int n0 = (nyz & 1) * 256;               // cluster tile
    const int koff0 = (nyz >> 1) * KT_PER * 32;   // K-slice start

    const size_t kbase = (size_t)koff0 + quad * 8;
    const unsigned short* aH[4];
    const unsigned short* bH[4];
    #pragma unroll
    for (int i = 0; i < 4; ++i)
        aH[i] = Qh + (size_t)(m0 + i * 16 + rlo) * KP + kbase;
    #pragma unroll
    for (int j2 = 0; j2 < 4; ++j2)
        bH[j2] = Bph + (size_t)(n0 + w * 64 + j2 * 16 + rlo) * KP + kbase;

    floatx4 acc[4][4] = {};

    short8 ahA[4], alA[4], bhA[4], blA[4];       // ping
    short8 ahB[4], alB[4], bhB[4], blB[4];       // pong

#define LOADSET(S, KO) {                                              \
    _Pragma("unroll")                                                 \
    for (int i = 0; i < 4; ++i) {                                     \
        ah##S[i] = *(const short8*)(aH[i] + (KO));                    \
        al##S[i] = *(const short8*)(aH[i] + QLOFF + (KO));            \
        bh##S[i] = *(const short8*)(bH[i] + (KO));                    \
        bl##S[i] = *(const short8*)(bH[i] + BLOFF + (KO));            \
    } }

#define MFMASET(S) {                                                  \
    __builtin_amdgcn_s_setprio(1);                                    \
    _Pragma("unroll")                                                 \
    for (int i = 0; i < 4; ++i)                                       \
        _Pragma("unroll")                                             \
        for (int j2 = 0; j2 < 4; ++j2) {                              \
            acc[i][j2] = __builtin_amdgcn_mfma_f32_16x16x32_bf16(al##S[i], bh##S[j2], acc[i][j2], 0, 0, 0); \
            acc[i][j2] = __builtin_amdgcn_mfma_f32_16x16x32_bf16(ah##S[i], bl##S[j2], acc[i][j2], 0, 0, 0); \
            acc[i][j2] = __builtin_amdgcn_mfma_f32_16x16x32_bf16(ah##S[i], bh##S[j2], acc[i][j2], 0, 0, 0); \
        }                                                             \
    __builtin_amdgcn_s_setprio(0); }

    LOADSET(A, 0)                                 // tile 0 in flight
    #pragma unroll 1
    for (int kt = 0; kt < KT_PER - 1; kt += 2) {  // pairs (0,1)..(14,15)
        LOADSET(B, (kt + 1) * 32)                 // tile kt+1 in flight
        MFMASET(A)                                // compute tile kt
        if (kt + 2 < KT_PER) LOADSET(A, (kt + 2) * 32)
        MFMASET(B)                                // compute tile kt+1
    }
    MFMASET(A)                                    // tile 16 (KT_PER odd)
#undef LOADSET
#undef MFMASET

    // C layout (verified m89): col = lane&15, row = (lane>>4)*4 + reg
    #pragma unroll
    for (int i = 0; i < 4; ++i)
        #pragma unroll
        for (int j2 = 0; j2 < 4; ++j2) {
            const int m = m0 + i * 16 + quad * 4;
            const int nn = n0 + w * 64 + j2 * 16 + rlo;
            #pragma unroll
            for (int r = 0; r < 4; ++r)
                atomicAdd(&d2[(size_t)(m + r) * NC + nn], acc[i][j2][r]);
        }
}

// ---------------- scores / argmaxes: 4 waves/block, one sample per wave -----
__global__ __launch_bounds__(256) void score_kernel(
    const float* __restrict__ d2, const float* __restrict__ labf,
    float* __restrict__ out)
{
    const int s = blockIdx.x * 4 + (threadIdx.x >> 6);
    const int l = threadIdx.x & 63;

    float numer[NK];
    #pragma unroll
    for (int q = 0; q < NK; ++q) numer[q] = 0.f;
    float denom = 0.f, gmax = -1.f;
    int gidx = 0;

    #pragma unroll
    for (int i = 0; i < NC / 256; ++i) {         // float4 per lane, index-ascending
        const int c0 = i * 256 + l * 4;
        const float4 v = *(const float4*)&d2[(size_t)s * NC + c0];
        #pragma unroll
        for (int r = 0; r < 4; ++r) {
            const int c = c0 + r;
            const float G = __expf(-0.5f * ((const float*)&v)[r]);
            denom += G;
            const int lab = (int)labf[c];
            #pragma unroll
            for (int q = 0; q < NK; ++q) numer[q] += (q == lab) ? G : 0.f;
            if (G > gmax) { gmax = G; gidx = c; }   // strict > keeps first index
        }
    }

    #pragma unroll
    for (int off = 32; off > 0; off >>= 1) {
        const float og = __shfl_down(gmax, off);
        const int   oi = __shfl_down(gidx, off);
        if (og > gmax || (og == gmax && oi < gidx)) { gmax = og; gidx = oi; }
        denom += __shfl_down(denom, off);
        #pragma unroll
        for (int q = 0; q < NK; ++q) numer[q] += __shfl_down(numer[q], off);
    }

    if (l == 0) {
        const float inv = 1.0f / (denom + 1e-12f);
        float best = -1.f; int pk = 0;
        #pragma unroll
        for (int q = 0; q < NK; ++q) {
            const float sc = numer[q] * inv;
            out[(size_t)s * NK + q] = sc;
            if (sc > best) { best = sc; pk = q; }
        }
        out[(size_t)NS * NK + s]      = (float)pk;    // pred
        out[(size_t)NS * NK + NS + s] = (float)gidx;  // clusters
    }
}

extern "C" void kernel_launch(void* const* d_in, const int* in_sizes, int n_in,
                              void* d_out, int out_size, void* d_ws, size_t ws_size,
                              hipStream_t stream)
{
    const float* data = (const float*)d_in[0];
    const float* n    = (const float*)d_in[2];
    const float* mu   = (const float*)d_in[3];
    const float* S    = (const float*)d_in[4];
    const int*   clab = (const int*)d_in[5];

    char* w = (char*)d_ws;
    unsigned short* Qh  = (unsigned short*)(w);                 // 17,825,792 B
    unsigned short* Ql  = (unsigned short*)(w + 17825792);      // 17,825,792 B (= Qh + QLOFF shorts)
    unsigned short* Bph = (unsigned short*)(w + 35651584);      //  2,228,224 B
    unsigned short* Bpl = (unsigned short*)(w + 37879808);      //  2,228,224 B (= Bph + BLOFF shorts)
    float* d2   = (float*)(w + 40108032);                       //  8,388,608 B
    float* labf = (float*)(w + 48496640);                       //      2,048 B
    uchar2* edt = (uchar2*)(w + 48498688);                      //      4,352 B

    hipLaunchKernelGGL(table_kernel, dim3(1), dim3(64), 0, stream, edt);
    hipLaunchKernelGGL(prep_kernel,  dim3(NC + ZB + QB), dim3(256), 0, stream,
                       data, S, n, mu, clab, edt, Qh, Ql, Bph, Bpl, d2, labf);
    hipLaunchKernelGGL(gemm_kernel,  dim3(NS / 64, NC / 256, KSPLIT), dim3(256), 0, stream,
                       Qh, Ql, Bph, Bpl, d2);
    hipLaunchKernelGGL(score_kernel, dim3(NS / 4), dim3(256), 0, stream,
                       d2, labf, (float*)d_out);
}